// Round 1
// baseline (166.713 us; speedup 1.0000x reference)
//
#include <hip/hip_runtime.h>
#include <math.h>

#define NCELL 10
#define EPSF 1e-7f

__global__ __launch_bounds__(256) void cpab_kernel(
    const float* __restrict__ x,
    const float* __restrict__ B,
    const float* __restrict__ W0, const float* __restrict__ b0,
    const float* __restrict__ W1, const float* __restrict__ b1,
    const float* __restrict__ W2, const float* __restrict__ b2,
    const float* __restrict__ W3, const float* __restrict__ b3,
    float* __restrict__ out, int N)
{
    // Per-thread (a,b) cell coefficients. Layout [cell][tid] so that the
    // dynamic-cell gather hits bank (tid % 32) -> conflict-free for any c.
    __shared__ float sAc[NCELL][256];
    __shared__ float sBc[NCELL][256];
    // Cell boundary table: sT[c] == (float)c / 10.0f with IEEE division,
    // matching the reference's c.astype(f32)/fnc exactly. (c*0.1f differs at c=9.)
    __shared__ float sT[NCELL + 1];

    const int tid = threadIdx.x;
    if (tid < NCELL + 1) sT[tid] = (float)tid / 10.0f;
    __syncthreads();

    const int i = blockIdx.x * 256 + tid;
    if (i >= N) return;

    // x is (N,2) row-major; coalesced 8B/lane load.
    const float2 xv = reinterpret_cast<const float2*>(x)[i];
    // mask=[1,0]: x1 = col 1 (MLP input), x2 = col 0 (integrated coord)
    const float hi_clip = 1.0f - 1e-7f;
    const float x2 = fminf(fmaxf(xv.x, EPSF), hi_clip);
    const float x1 = fminf(fmaxf(xv.y, EPSF), hi_clip);

    // ---- MLP: 1 -> 10 -> 10 -> 10 -> 9 (weights uniform -> scalar loads) ----
    float h0[10], h1[10], h2[10];
    #pragma unroll
    for (int j = 0; j < 10; ++j)
        h0[j] = fmaxf(fmaf(x1, W0[j], b0[j]), 0.0f);
    #pragma unroll
    for (int j = 0; j < 10; ++j) {
        float acc = b1[j];
        #pragma unroll
        for (int k = 0; k < 10; ++k) acc = fmaf(h0[k], W1[k * 10 + j], acc);
        h1[j] = fmaxf(acc, 0.0f);
    }
    #pragma unroll
    for (int j = 0; j < 10; ++j) {
        float acc = b2[j];
        #pragma unroll
        for (int k = 0; k < 10; ++k) acc = fmaf(h1[k], W2[k * 10 + j], acc);
        h2[j] = fmaxf(acc, 0.0f);
    }
    float theta[9];
    #pragma unroll
    for (int j = 0; j < 9; ++j) {
        float acc = b3[j];
        #pragma unroll
        for (int k = 0; k < 10; ++k) acc = fmaf(h2[k], W3[k * 9 + j], acc);
        theta[j] = acc;
    }

    // ---- A = theta @ B.T, B is (20,9) row-major. A[2m]=a_m, A[2m+1]=b_m ----
    #pragma unroll
    for (int m = 0; m < NCELL; ++m) {
        float am = 0.0f, bm = 0.0f;
        #pragma unroll
        for (int j = 0; j < 9; ++j) {
            am = fmaf(theta[j], B[(2 * m) * 9 + j], am);
            bm = fmaf(theta[j], B[(2 * m + 1) * 9 + j], bm);
        }
        sAc[m][tid] = am;
        sBc[m][tid] = bm;
    }
    // No __syncthreads needed: each thread reads only its own [.,tid] slots.

    // ---- CPAB integration: 11-step scan with cell crossing ----
    float phi = x2;
    int   c   = (int)floorf(x2 * 10.0f);
    c = min(max(c, 0), NCELL - 1);
    float t = 1.0f, s = 0.0f;
    bool done = false;

    #pragma unroll 1
    for (int it = 0; it < NCELL + 1; ++it) {
        const float a = sAc[c][tid];
        const float b = sBc[c][tid];
        const float v = fmaf(a, phi, b);
        const bool  big    = fabsf(a) > 1e-10f;
        const float a_safe = big ? a : 1.0f;
        const float boa    = b / a_safe;
        const float e      = expf(a * t);
        const float psi    = big ? ((phi + boa) * e - boa) : fmaf(b, t, phi);
        const float lo = sT[c];
        const float hi = sT[c + 1];
        const bool  inside = (psi >= lo) && (psi <= hi);
        const float xc     = (v >= 0.0f) ? hi : lo;
        const float vb     = fmaf(a, xc, b);
        const float v_safe = (v == 0.0f) ? 1.0f : v;
        const float ratio  = fmaxf(vb / v_safe, 1e-30f);
        const float t_hit  = big ? (logf(ratio) / a_safe) : ((xc - phi) / v_safe);

        const bool act   = !done;
        const bool cross = act && !inside;
        if (act) s += a * (inside ? t : t_hit);
        phi = cross ? xc : ((act && inside) ? psi : phi);
        if (cross) {
            t = t - t_hit;
            c = min(max(c + ((v >= 0.0f) ? 1 : -1), 0), NCELL - 1);
        }
        done = done || inside;
        // Exact: post-all-done iterations are no-ops in the reference scan.
        if (__all(done)) break;
    }

    // ---- outputs: z = [z2, x1] interleaved; log_dz_dx = [log(exp(s)), 0] ----
    const float es = expf(s);
    reinterpret_cast<float2*>(out)[i] = make_float2(phi, x1);
    reinterpret_cast<float2*>(out + (size_t)2 * N)[i] = make_float2(logf(es), 0.0f);
}

extern "C" void kernel_launch(void* const* d_in, const int* in_sizes, int n_in,
                              void* d_out, int out_size, void* d_ws, size_t ws_size,
                              hipStream_t stream) {
    (void)n_in; (void)out_size; (void)d_ws; (void)ws_size;
    const float* x  = (const float*)d_in[0];
    const float* B  = (const float*)d_in[1];
    const float* W0 = (const float*)d_in[2];
    const float* b0 = (const float*)d_in[3];
    const float* W1 = (const float*)d_in[4];
    const float* b1 = (const float*)d_in[5];
    const float* W2 = (const float*)d_in[6];
    const float* b2 = (const float*)d_in[7];
    const float* W3 = (const float*)d_in[8];
    const float* b3 = (const float*)d_in[9];
    float* out = (float*)d_out;

    const int N = in_sizes[0] / 2;
    const int block = 256;
    const int grid = (N + block - 1) / block;
    cpab_kernel<<<grid, block, 0, stream>>>(x, B, W0, b0, W1, b1, W2, b2, W3, b3, out, N);
}